// Round 10
// baseline (623.131 us; speedup 1.0000x reference)
//
#include <hip/hip_runtime.h>

#define NN 50000
#define EE 1600000
#define SCAN_B 196   // ceil(NN/256)
#define NB 196       // buckets = dst >> 8
#define CHUNK 2048   // edges per wg in radix passes
#define G1 782       // ceil(EE/CHUNK)
#define L1 (NB * G1) // count-matrix length = 153272
#define B1 599       // ceil(L1/256)

typedef __attribute__((ext_vector_type(8))) short bf16x8;
typedef __attribute__((ext_vector_type(4))) float f32x4;
typedef __attribute__((ext_vector_type(2))) float f32x2;

#if __has_builtin(__builtin_elementwise_fma)
#define PKFMA(a, b, c) __builtin_elementwise_fma((a), (b), (c))
#else
#define PKFMA(a, b, c) ((a) * (b) + (c))
#endif

__device__ __forceinline__ float bfu(unsigned short u) { return __uint_as_float((unsigned)u << 16); }
__device__ __forceinline__ float bflo(unsigned u) { return __uint_as_float(u << 16); }
__device__ __forceinline__ float bfhi(unsigned u) { return __uint_as_float(u & 0xffff0000u); }
__device__ __forceinline__ f32x2 bfpk(unsigned u) {
    f32x2 r; r.x = bflo(u); r.y = bfhi(u); return r;
}
__device__ __forceinline__ unsigned short f2bf(float f) {   // RNE f32->bf16
    unsigned u = __float_as_uint(f);
    u += 0x7fff + ((u >> 16) & 1);
    return (unsigned short)(u >> 16);
}
__device__ __forceinline__ unsigned pk2(float a, float b) {
    return (unsigned)f2bf(a) | ((unsigned)f2bf(b) << 16);
}
__device__ __forceinline__ float cvt_load(const void* p, int i, bool f32) {
    if (f32) return ((const float*)p)[i];
    return bfu(((const unsigned short*)p)[i]);
}

// ---------------- dtype detection ----------------
__global__ void detect_k(const void* ei_raw, const void* x_raw, int* flags) {
    __shared__ int s_i64, s_f32;
    const int t = threadIdx.x;
    if (t == 0) { s_i64 = 1; s_f32 = 0; }
    __syncthreads();
    const int* ei32 = (const int*)ei_raw;
    if (ei32[2 * t + 1] != 0) atomicAnd(&s_i64, 0);
    const unsigned short* xu = (const unsigned short*)x_raw;
    int found = 0;
    for (int j = 0; j < 32; j++) {
        unsigned short u = xu[t * 32 + j];
        if ((u & 0x7F80) == 0x7F80) found = 1;
    }
    if (found) atomicOr(&s_f32, 1);
    __syncthreads();
    if (t == 0) { flags[0] = s_i64; flags[1] = s_f32; }
}

// ---------------- radix pass 1: normalize + per-(bucket,wg) histogram + global deg ----------------
__global__ __launch_bounds__(256) void hist1_k(const void* ei_raw, const int* flags,
                                               int2* __restrict__ edges, int* __restrict__ cnt,
                                               int* __restrict__ deg)
{
    __shared__ int h[NB];
    const int t = threadIdx.x;
    const int i64 = __builtin_amdgcn_readfirstlane(flags[0]);
    if (t < NB) h[t] = 0;
    __syncthreads();
    const int beg = blockIdx.x * CHUNK;
    const int end = min(beg + CHUNK, EE);
    for (int e = beg + t; e < end; e += 256) {
        int2 v;
        if (i64) { const long long* p = (const long long*)ei_raw; v.x = (int)p[e]; v.y = (int)p[EE + e]; }
        else     { const int* p = (const int*)ei_raw;             v.x = p[e];      v.y = p[EE + e];      }
        edges[e] = v;
        atomicAdd(&h[v.y >> 8], 1);
        atomicAdd(&deg[v.y], 1);                    // 200KB L2-resident table
    }
    __syncthreads();
    if (t < NB) cnt[(size_t)t * G1 + blockIdx.x] = h[t];
}

// ---------------- generic scan over cnt[L1] (3-phase) ----------------
__global__ __launch_bounds__(256) void scanAg_k(int* __restrict__ cnt, int* __restrict__ bsum2) {
    __shared__ int ps[256];
    const int b = blockIdx.x, t = threadIdx.x;
    const int i = b * 256 + t;
    const int v = (i < L1) ? cnt[i] : 0;
    ps[t] = v;
    __syncthreads();
    for (int off = 1; off < 256; off <<= 1) {
        const int u = (t >= off) ? ps[t - off] : 0;
        __syncthreads();
        ps[t] += u;
        __syncthreads();
    }
    if (i < L1) cnt[i] = ps[t] - v;            // local exclusive
    if (t == 255) bsum2[b] = ps[255];
}
__global__ void scanBg_k(int* bsum2) {
    __shared__ int ps[256];
    const int t = threadIdx.x;
    int vals[3];
    int s = 0;
    #pragma unroll
    for (int i = 0; i < 3; i++) {
        const int idx = t * 3 + i;
        vals[i] = (idx < B1) ? bsum2[idx] : 0;
        s += vals[i];
    }
    ps[t] = s;
    __syncthreads();
    for (int off = 1; off < 256; off <<= 1) {
        const int u = (t >= off) ? ps[t - off] : 0;
        __syncthreads();
        ps[t] += u;
        __syncthreads();
    }
    int run = t ? ps[t - 1] : 0;
    #pragma unroll
    for (int i = 0; i < 3; i++) {
        const int idx = t * 3 + i;
        if (idx < B1) bsum2[idx] = run;
        run += vals[i];
    }
}
__global__ __launch_bounds__(256) void scanCg_k(int* __restrict__ cnt, const int* __restrict__ bsum2,
                                                int* __restrict__ bstart) {
    const int i = blockIdx.x * 256 + threadIdx.x;
    if (i < L1) {
        const int r = cnt[i] + bsum2[blockIdx.x];
        cnt[i] = r;
        if (i % G1 == 0) bstart[i / G1] = r;
    }
    if (i == 0) bstart[NB] = EE;
}

// ---------------- radix pass 2: deterministic scatter into bucket-contiguous bedges ----------------
__global__ __launch_bounds__(256) void scatter_k(const int2* __restrict__ edges,
                                                 const int* __restrict__ cnt,
                                                 int2* __restrict__ bedges)
{
    __shared__ int ofs[NB];
    const int t = threadIdx.x;
    if (t < NB) ofs[t] = cnt[(size_t)t * G1 + blockIdx.x];
    __syncthreads();
    const int beg = blockIdx.x * CHUNK;
    const int end = min(beg + CHUNK, EE);
    for (int e = beg + t; e < end; e += 256) {
        const int2 v = edges[e];
        const int p = atomicAdd(&ofs[v.y >> 8], 1);        // LDS atomic
        bedges[p] = v;
    }
}

// ---------------- node-level 3-phase scan ----------------
__global__ __launch_bounds__(256) void scanA_k(const int* __restrict__ deg,
                                               int* __restrict__ roff, int* __restrict__ bsum) {
    __shared__ int ps[256];
    const int b = blockIdx.x, t = threadIdx.x;
    const int i = b * 256 + t;
    const int v = (i < NN) ? deg[i] : 0;
    ps[t] = v;
    __syncthreads();
    for (int off = 1; off < 256; off <<= 1) {
        const int u = (t >= off) ? ps[t - off] : 0;
        __syncthreads();
        ps[t] += u;
        __syncthreads();
    }
    if (i < NN) roff[i] = ps[t] - v;           // local exclusive
    if (t == 255) bsum[b] = ps[255];
}
__global__ void scanB_k(int* bsum) {
    __shared__ int ps[256];
    const int t = threadIdx.x;
    const int v = (t < SCAN_B) ? bsum[t] : 0;
    ps[t] = v;
    __syncthreads();
    for (int off = 1; off < 256; off <<= 1) {
        const int u = (t >= off) ? ps[t - off] : 0;
        __syncthreads();
        ps[t] += u;
        __syncthreads();
    }
    if (t < SCAN_B) bsum[t] = ps[t] - v;       // exclusive block base
}
__global__ __launch_bounds__(256) void scanC_k(int* __restrict__ roff, const int* __restrict__ bsum) {
    const int b = blockIdx.x, t = threadIdx.x;
    const int i = b * 256 + t;
    if (i < NN) roff[i] += bsum[b];
}

// ---------------- per-bucket CSR placement (LDS cursors; writes confined to one wg) ----------------
__global__ __launch_bounds__(256) void place_k(const int2* __restrict__ bedges,
                                               const int* __restrict__ bstart, const int* __restrict__ roff,
                                               int* __restrict__ csrc)
{
    __shared__ int cur[256];
    const int b = blockIdx.x, t = threadIdx.x;
    const int d = b * 256 + t;
    cur[t] = (d < NN) ? roff[d] : 0;
    __syncthreads();
    const int lo = bstart[b], hi = bstart[b + 1];
    for (int i = lo + t; i < hi; i += 256) {
        const int2 v = bedges[i];
        const int p = atomicAdd(&cur[v.y & 255], 1);       // LDS atomic
        csrc[p] = v.x;
    }
}

// ---------------- normalize: x->bf16, W->transposed bf16, smalls->f32 ----------------
__global__ __launch_bounds__(256) void cvt_all_k(
    const void* x, const void* W1, const void* Wskip, const void* W2, const void* W3,
    const void* as1, const void* ad1, const void* b1, const void* l1w, const void* l1b,
    const void* bsk, const void* as2, const void* ad2, const void* b2, const void* l2w,
    const void* l2b, const void* as3, const void* ad3, const void* b3,
    unsigned short* xb, unsigned short* Wt1, unsigned short* Wts, unsigned short* Wt2,
    unsigned short* Wt3, float* smalls, const int* flags)
{
    const bool f32 = __builtin_amdgcn_readfirstlane(flags[1]) != 0;
    const int gid = blockIdx.x * 256 + threadIdx.x;
    if (gid < NN * 128) { xb[gid] = f2bf(cvt_load(x, gid, f32)); return; }
    int g = gid - NN * 128;
    if (g < 16384) { Wt1[g] = f2bf(cvt_load(W1,    (g & 127) * 128 + (g >> 7), f32)); return; }
    g -= 16384;
    if (g < 16384) { Wts[g] = f2bf(cvt_load(Wskip, (g & 127) * 128 + (g >> 7), f32)); return; }
    g -= 16384;
    if (g < 16384) { Wt2[g] = f2bf(cvt_load(W2,    (g & 127) * 128 + (g >> 7), f32)); return; }
    g -= 16384;
    if (g < 32768) { Wt3[g] = f2bf(cvt_load(W3,    (g & 127) * 256 + (g >> 7), f32)); return; }
    g -= 32768;
    if (g >= 2432) return;
    const void* src; int off;
    if      (g < 128)  { src = as1; off = g;        }
    else if (g < 256)  { src = ad1; off = g - 128;  }
    else if (g < 384)  { src = b1;  off = g - 256;  }
    else if (g < 512)  { src = l1w; off = g - 384;  }
    else if (g < 640)  { src = l1b; off = g - 512;  }
    else if (g < 768)  { src = bsk; off = g - 640;  }
    else if (g < 896)  { src = as2; off = g - 768;  }
    else if (g < 1024) { src = ad2; off = g - 896;  }
    else if (g < 1152) { src = b2;  off = g - 1024; }
    else if (g < 1280) { src = l2w; off = g - 1152; }
    else if (g < 1408) { src = l2b; off = g - 1280; }
    else if (g < 1664) { src = as3; off = g - 1408; }
    else if (g < 1920) { src = ad3; off = g - 1664; }
    else               { src = b3;  off = g - 1920; }
    smalls[g] = cvt_load(src, off, f32);
}

// ---------------- v_h = W3_h @ a3_h composites (for layer-3 logits) ----------------
__global__ void prep_v_k(const unsigned short* __restrict__ Wt3, const float* __restrict__ as3,
                         const float* __restrict__ ad3, float* __restrict__ vsrc, float* __restrict__ vdst)
{
    const int t = blockIdx.x * 256 + threadIdx.x;   // 512 total
    if (t >= 512) return;
    const int h = t >> 7, k = t & 127;
    float ss = 0.f, dd = 0.f;
    for (int c = 0; c < 64; c++) {
        const float w = bfu(Wt3[(size_t)(h * 64 + c) * 128 + k]);
        ss = fmaf(w, as3[h * 64 + c], ss);
        dd = fmaf(w, ad3[h * 64 + c], dd);
    }
    vsrc[t] = ss; vdst[t] = dd;
}

// ---------------- MFMA matmul + optional fused attention dots ----------------
template<int FOUT, bool DOTS>
__global__ __launch_bounds__(256) void mfma_mm_k(
    const unsigned short* __restrict__ Xb, const unsigned short* __restrict__ Wt,
    unsigned short* __restrict__ Hb,
    const float* __restrict__ asrc, const float* __restrict__ adst,
    float* __restrict__ as_, float* __restrict__ dpk)
{
    constexpr int NT = FOUT / 16;
    const int tile = blockIdx.x * 4 + (threadIdx.x >> 6);
    if (tile >= 3125) return;                       // 50000 = 3125*16
    const int l = threadIdx.x & 63;
    const int lr = l & 15, lq = l >> 4;
    const int m0 = tile * 16;
    f32x4 acc[NT];
    #pragma unroll
    for (int nt = 0; nt < NT; nt++) { acc[nt][0]=0.f; acc[nt][1]=0.f; acc[nt][2]=0.f; acc[nt][3]=0.f; }
    #pragma unroll
    for (int kb = 0; kb < 4; kb++) {                // K=128 = 4*32
        const bf16x8 a = *(const bf16x8*)(Xb + (size_t)(m0 + lr) * 128 + kb * 32 + lq * 8);
        #pragma unroll
        for (int nt = 0; nt < NT; nt++) {
            const bf16x8 b = *(const bf16x8*)(Wt + (size_t)(nt * 16 + lr) * 128 + kb * 32 + lq * 8);
            acc[nt] = __builtin_amdgcn_mfma_f32_16x16x32_bf16(a, b, acc[nt], 0, 0, 0);
        }
    }
    #pragma unroll
    for (int nt = 0; nt < NT; nt++)
        #pragma unroll
        for (int r = 0; r < 4; r++)
            Hb[(size_t)(m0 + lq * 4 + r) * FOUT + nt * 16 + lr] = f2bf(acc[nt][r]);
    if (DOTS) {
        #pragma unroll
        for (int hd = 0; hd < 4; hd++) {
            const float a0 = asrc[hd * 32 + lr], a1 = asrc[hd * 32 + 16 + lr];
            const float d0 = adst[hd * 32 + lr], d1 = adst[hd * 32 + 16 + lr];
            #pragma unroll
            for (int r = 0; r < 4; r++) {
                float ps = acc[2 * hd][r] * a0 + acc[2 * hd + 1][r] * a1;
                float pd = acc[2 * hd][r] * d0 + acc[2 * hd + 1][r] * d1;
                #pragma unroll
                for (int m = 8; m; m >>= 1) { ps += __shfl_xor(ps, m); pd += __shfl_xor(pd, m); }
                if (lr == 0) {
                    const int node = m0 + lq * 4 + r;
                    as_[(size_t)node * 4 + hd] = ps;
                    dpk[(size_t)node * 8 + hd] = pd;
                }
            }
        }
    }
}

// ---------------- fused layer-1 matmul: H = X@W1t^T, S = X@Wst^T, + dots1 ----------------
__global__ __launch_bounds__(256) void mm12_k(
    const unsigned short* __restrict__ Xb, const unsigned short* __restrict__ Wt1,
    unsigned short* __restrict__ Hb, unsigned short* __restrict__ Sb,
    const float* __restrict__ asrc, const float* __restrict__ adst,
    float* __restrict__ as_, float* __restrict__ dpk)
{
    const int tile = blockIdx.x * 4 + (threadIdx.x >> 6);
    if (tile >= 3125) return;
    const int l = threadIdx.x & 63;
    const int lr = l & 15, lq = l >> 4;
    const int m0 = tile * 16;
    f32x4 acc[16];
    #pragma unroll
    for (int nt = 0; nt < 16; nt++) { acc[nt][0]=0.f; acc[nt][1]=0.f; acc[nt][2]=0.f; acc[nt][3]=0.f; }
    #pragma unroll
    for (int kb = 0; kb < 4; kb++) {
        const bf16x8 a = *(const bf16x8*)(Xb + (size_t)(m0 + lr) * 128 + kb * 32 + lq * 8);
        #pragma unroll
        for (int nt = 0; nt < 16; nt++) {
            const bf16x8 b = *(const bf16x8*)(Wt1 + (size_t)(nt * 16 + lr) * 128 + kb * 32 + lq * 8);
            acc[nt] = __builtin_amdgcn_mfma_f32_16x16x32_bf16(a, b, acc[nt], 0, 0, 0);
        }
    }
    #pragma unroll
    for (int nt = 0; nt < 8; nt++)
        #pragma unroll
        for (int r = 0; r < 4; r++)
            Hb[(size_t)(m0 + lq * 4 + r) * 128 + nt * 16 + lr] = f2bf(acc[nt][r]);
    #pragma unroll
    for (int nt = 8; nt < 16; nt++)
        #pragma unroll
        for (int r = 0; r < 4; r++)
            Sb[(size_t)(m0 + lq * 4 + r) * 128 + (nt - 8) * 16 + lr] = f2bf(acc[nt][r]);
    #pragma unroll
    for (int hd = 0; hd < 4; hd++) {
        const float a0 = asrc[hd * 32 + lr], a1 = asrc[hd * 32 + 16 + lr];
        const float d0 = adst[hd * 32 + lr], d1 = adst[hd * 32 + 16 + lr];
        #pragma unroll
        for (int r = 0; r < 4; r++) {
            float ps = acc[2 * hd][r] * a0 + acc[2 * hd + 1][r] * a1;
            float pd = acc[2 * hd][r] * d0 + acc[2 * hd + 1][r] * d1;
            #pragma unroll
            for (int m = 8; m; m >>= 1) { ps += __shfl_xor(ps, m); pd += __shfl_xor(pd, m); }
            if (lr == 0) {
                const int node = m0 + lq * 4 + r;
                as_[(size_t)node * 4 + hd] = ps;
                dpk[(size_t)node * 8 + hd] = pd;
            }
        }
    }
}

__device__ __forceinline__ float4 edge_w(float4 as4, float4 ad4) {
    float4 e4;
    e4.x = as4.x + ad4.x; e4.y = as4.y + ad4.y; e4.z = as4.z + ad4.z; e4.w = as4.w + ad4.w;
    e4.x = e4.x >= 0.f ? e4.x : 0.2f * e4.x;
    e4.y = e4.y >= 0.f ? e4.y : 0.2f * e4.y;
    e4.z = e4.z >= 0.f ? e4.z : 0.2f * e4.z;
    e4.w = e4.w >= 0.f ? e4.w : 0.2f * e4.w;
    float4 w4;
    w4.x = __expf(e4.x); w4.y = __expf(e4.y); w4.z = __expf(e4.z); w4.w = __expf(e4.w);
    return w4;
}

// ---------------- fused edge phase, layers 1/2: 2 nodes per wave (half-wave each) ----------------
template<bool HAS_SKIP, bool DOTS3>
__global__ __launch_bounds__(256) void fagg12_k(
    const int* __restrict__ roff, const int* __restrict__ deg,
    const int* __restrict__ csrc, const float* __restrict__ as_, float* __restrict__ dpk,
    const unsigned short* __restrict__ Hb,
    const float* __restrict__ b, const float* __restrict__ lnw, const float* __restrict__ lnb,
    const unsigned short* __restrict__ skipb, const float* __restrict__ bskip,
    unsigned short* __restrict__ xoutb,
    const float* __restrict__ vsrc, const float* __restrict__ vdst,
    float* __restrict__ as3o, float* __restrict__ dpk3o)
{
    __shared__ float lws[4][512];                   // per wave: 2 halves x 32 edges x [w0,s,w1,s,w2,s,w3,s]
    const int warp = threadIdx.x >> 6;
    const int lane = threadIdx.x & 63;
    const int half = lane >> 5;                     // node selector within wave
    const int l32  = lane & 31;
    const int node = blockIdx.x * 8 + warp * 2 + half;
    const int q = l32 & 15, g = l32 >> 4;           // features 8q..8q+7 ; edge group g (0/1)
    const int h = q >> 2;                           // head of this lane's features
    float* lw = lws[warp] + half * 256;
    const int ro = roff[node], dg = deg[node];
    const float4 ad4 = *(const float4*)(dpk + (size_t)node * 8);

    float4 sv = make_float4(0.f, 0.f, 0.f, 0.f);
    f32x2 acc2[4];
    #pragma unroll
    for (int i = 0; i < 4; i++) { acc2[i].x = 0.f; acc2[i].y = 0.f; }

    for (int j0 = 0; j0 < dg; j0 += 32) {
        const int jn = min(32, dg - j0);
        int src = 0;
        float4 w4 = make_float4(0.f, 0.f, 0.f, 0.f);
        if (l32 < jn) {
            src = csrc[ro + j0 + l32];
            const float4 as4 = *(const float4*)(as_ + (size_t)src * 4);
            w4 = edge_w(as4, ad4);
            sv.x += w4.x; sv.y += w4.y; sv.z += w4.z; sv.w += w4.w;
        }
        const float sf = __int_as_float(src);
        *(float4*)(lw + l32 * 8)     = make_float4(w4.x, sf, w4.y, sf);
        *(float4*)(lw + l32 * 8 + 4) = make_float4(w4.z, sf, w4.w, sf);
        const int jq = (jn + 1) >> 1;
        #pragma unroll 4
        for (int j = 0; j < jq; j++) {
            const int e = 2 * j + g;                // e==jn (odd tail) reads w=0 entry: harmless
            const float2 rd = *(const float2*)(lw + e * 8 + h * 2);  // (w_h, src bits) broadcast
            f32x2 ww; ww.x = rd.x; ww.y = rd.x;
            const unsigned soff = (__float_as_uint(rd.y) << 8) + (unsigned)(q << 4);
            const uint4 hv = *(const uint4*)((const char*)Hb + soff); // 16B of row
            acc2[0] = PKFMA(ww, bfpk(hv.x), acc2[0]);
            acc2[1] = PKFMA(ww, bfpk(hv.y), acc2[1]);
            acc2[2] = PKFMA(ww, bfpk(hv.z), acc2[2]);
            acc2[3] = PKFMA(ww, bfpk(hv.w), acc2[3]);
        }
    }

    // combine the 2 edge-groups' partial sums (stay within the 32-lane half)
    #pragma unroll
    for (int i = 0; i < 4; i++) {
        acc2[i].x += __shfl_xor(acc2[i].x, 16);
        acc2[i].y += __shfl_xor(acc2[i].y, 16);
    }
    #pragma unroll
    for (int m = 16; m; m >>= 1) {
        sv.x += __shfl_xor(sv.x, m); sv.y += __shfl_xor(sv.y, m);
        sv.z += __shfl_xor(sv.z, m); sv.w += __shfl_xor(sv.w, m);
    }
    float4 rs;
    rs.x = 1.f / (sv.x + 1e-16f); rs.y = 1.f / (sv.y + 1e-16f);
    rs.z = 1.f / (sv.z + 1e-16f); rs.w = 1.f / (sv.w + 1e-16f);
    if (l32 == 0) *(float4*)(dpk + (size_t)node * 8 + 4) = rs;
    const float rsh = (h == 0) ? rs.x : (h == 1) ? rs.y : (h == 2) ? rs.z : rs.w;

    // epilogue: bias -> elu -> LN (+skip) -> bf16 pack (both groups replicated; g==0 stores)
    const float4 b0 = *(const float4*)(b + q * 8);
    const float4 b1 = *(const float4*)(b + q * 8 + 4);
    float v[8];
    v[0] = acc2[0].x * rsh + b0.x; v[1] = acc2[0].y * rsh + b0.y;
    v[2] = acc2[1].x * rsh + b0.z; v[3] = acc2[1].y * rsh + b0.w;
    v[4] = acc2[2].x * rsh + b1.x; v[5] = acc2[2].y * rsh + b1.y;
    v[6] = acc2[3].x * rsh + b1.z; v[7] = acc2[3].y * rsh + b1.w;
    float s1 = 0.f, s2 = 0.f;
    #pragma unroll
    for (int i = 0; i < 8; i++) {
        v[i] = v[i] > 0.f ? v[i] : (__expf(v[i]) - 1.f);
        s1 += v[i]; s2 += v[i] * v[i];
    }
    #pragma unroll
    for (int m = 8; m; m >>= 1) { s1 += __shfl_xor(s1, m); s2 += __shfl_xor(s2, m); }
    const float mu   = s1 * (1.f / 128.f);
    const float var  = s2 * (1.f / 128.f) - mu * mu;
    const float rstd = rsqrtf(var + 1e-5f);
    const float4 w0 = *(const float4*)(lnw + q * 8);
    const float4 w1 = *(const float4*)(lnw + q * 8 + 4);
    const float4 o0 = *(const float4*)(lnb + q * 8);
    const float4 o1 = *(const float4*)(lnb + q * 8 + 4);
    float y[8];
    y[0] = (v[0] - mu) * rstd * w0.x + o0.x; y[1] = (v[1] - mu) * rstd * w0.y + o0.y;
    y[2] = (v[2] - mu) * rstd * w0.z + o0.z; y[3] = (v[3] - mu) * rstd * w0.w + o0.w;
    y[4] = (v[4] - mu) * rstd * w1.x + o1.x; y[5] = (v[5] - mu) * rstd * w1.y + o1.y;
    y[6] = (v[6] - mu) * rstd * w1.z + o1.z; y[7] = (v[7] - mu) * rstd * w1.w + o1.w;
    if (HAS_SKIP) {
        const uint4 sk = *(const uint4*)(skipb + (size_t)node * 128 + q * 8);
        const float4 k0 = *(const float4*)(bskip + q * 8);
        const float4 k1 = *(const float4*)(bskip + q * 8 + 4);
        y[0] += bflo(sk.x) + k0.x; y[1] += bfhi(sk.x) + k0.y;
        y[2] += bflo(sk.y) + k0.z; y[3] += bfhi(sk.y) + k0.w;
        y[4] += bflo(sk.z) + k1.x; y[5] += bfhi(sk.z) + k1.y;
        y[6] += bflo(sk.w) + k1.z; y[7] += bfhi(sk.w) + k1.w;
    }
    if (g == 0) {
        uint4 pk;
        pk.x = pk2(y[0], y[1]); pk.y = pk2(y[2], y[3]);
        pk.z = pk2(y[4], y[5]); pk.w = pk2(y[6], y[7]);
        *(uint4*)(xoutb + (size_t)node * 128 + q * 8) = pk;
    }
    if (DOTS3) {
        // layer-3 logits from register-resident y (feats 8q..8q+7)
        #pragma unroll
        for (int hd = 0; hd < 4; hd++) {
            const float4 vs0 = *(const float4*)(vsrc + hd * 128 + q * 8);
            const float4 vs1 = *(const float4*)(vsrc + hd * 128 + q * 8 + 4);
            const float4 vd0 = *(const float4*)(vdst + hd * 128 + q * 8);
            const float4 vd1 = *(const float4*)(vdst + hd * 128 + q * 8 + 4);
            float ss = y[0] * vs0.x + y[1] * vs0.y + y[2] * vs0.z + y[3] * vs0.w
                     + y[4] * vs1.x + y[5] * vs1.y + y[6] * vs1.z + y[7] * vs1.w;
            float dd = y[0] * vd0.x + y[1] * vd0.y + y[2] * vd0.z + y[3] * vd0.w
                     + y[4] * vd1.x + y[5] * vd1.y + y[6] * vd1.z + y[7] * vd1.w;
            #pragma unroll
            for (int m = 8; m; m >>= 1) { ss += __shfl_xor(ss, m); dd += __shfl_xor(dd, m); }
            if (l32 == 0) {
                as3o[(size_t)node * 4 + hd] = ss;
                dpk3o[(size_t)node * 8 + hd] = dd;
            }
        }
    }
}

// ---------------- layer-3 edge phase: 2 nodes/wave, 32 lanes/edge, 4x unrolled gathers ----------------
__global__ __launch_bounds__(256) void fagg3_k(
    const int* __restrict__ roff, const int* __restrict__ deg,
    const int* __restrict__ csrc, const float* __restrict__ as_, float* __restrict__ dpk,
    const unsigned short* __restrict__ Xb,
    unsigned short* __restrict__ gout)
{
    __shared__ float lws[4][256];                   // 2 halves x 32 edges x w4
    __shared__ int lss[4][64];                      // 2 halves x 32 src
    const int warp = threadIdx.x >> 6;
    const int lane = threadIdx.x & 63;
    const int half = lane >> 5;
    const int l32  = lane & 31;
    const int node = blockIdx.x * 8 + warp * 2 + half;
    float* lw = lws[warp] + half * 128;
    int*   ls = lss[warp] + half * 32;
    const int ro = roff[node], dg = deg[node];
    const float4 ad4 = *(const float4*)(dpk + (size_t)node * 8);

    float4 sv = make_float4(0.f, 0.f, 0.f, 0.f);
    f32x2 acc2[4][2];
    #pragma unroll
    for (int hh = 0; hh < 4; hh++)
        #pragma unroll
        for (int i = 0; i < 2; i++) { acc2[hh][i].x = 0.f; acc2[hh][i].y = 0.f; }

    const unsigned myoff = (unsigned)(l32 << 3);    // 8B feature slice: feats 4*l32..4*l32+3

    #define F3_FMA(W4, HV)                                                              \
        {                                                                               \
            const f32x2 x01 = bfpk((HV).x), x23 = bfpk((HV).y);                         \
            f32x2 w0; w0.x = (W4).x; w0.y = (W4).x;                                     \
            f32x2 w1; w1.x = (W4).y; w1.y = (W4).y;                                     \
            f32x2 w2; w2.x = (W4).z; w2.y = (W4).z;                                     \
            f32x2 w3; w3.x = (W4).w; w3.y = (W4).w;                                     \
            acc2[0][0] = PKFMA(w0, x01, acc2[0][0]); acc2[0][1] = PKFMA(w0, x23, acc2[0][1]); \
            acc2[1][0] = PKFMA(w1, x01, acc2[1][0]); acc2[1][1] = PKFMA(w1, x23, acc2[1][1]); \
            acc2[2][0] = PKFMA(w2, x01, acc2[2][0]); acc2[2][1] = PKFMA(w2, x23, acc2[2][1]); \
            acc2[3][0] = PKFMA(w3, x01, acc2[3][0]); acc2[3][1] = PKFMA(w3, x23, acc2[3][1]); \
        }

    for (int j0 = 0; j0 < dg; j0 += 32) {
        const int jn = min(32, dg - j0);
        int src = 0;
        float4 w4 = make_float4(0.f, 0.f, 0.f, 0.f);
        if (l32 < jn) {
            src = csrc[ro + j0 + l32];
            const float4 as4 = *(const float4*)(as_ + (size_t)src * 4);
            w4 = edge_w(as4, ad4);
            sv.x += w4.x; sv.y += w4.y; sv.z += w4.z; sv.w += w4.w;
        }
        *(float4*)(lw + l32 * 4) = w4;
        ls[l32] = src;
        int j = 0;
        for (; j + 4 <= jn; j += 4) {               // 4 independent gather chains in flight
            const float4 wa = *(const float4*)(lw + j * 4);
            const float4 wb = *(const float4*)(lw + j * 4 + 4);
            const float4 wc = *(const float4*)(lw + j * 4 + 8);
            const float4 wd = *(const float4*)(lw + j * 4 + 12);
            const int sa = ls[j], sb = ls[j + 1], sc = ls[j + 2], sd = ls[j + 3];
            const uint2 ha = *(const uint2*)((const char*)Xb + (((unsigned)sa) << 8) + myoff);
            const uint2 hb = *(const uint2*)((const char*)Xb + (((unsigned)sb) << 8) + myoff);
            const uint2 hc = *(const uint2*)((const char*)Xb + (((unsigned)sc) << 8) + myoff);
            const uint2 hd = *(const uint2*)((const char*)Xb + (((unsigned)sd) << 8) + myoff);
            F3_FMA(wa, ha)
            F3_FMA(wb, hb)
            F3_FMA(wc, hc)
            F3_FMA(wd, hd)
        }
        for (; j + 2 <= jn; j += 2) {
            const float4 wa = *(const float4*)(lw + j * 4);
            const float4 wb = *(const float4*)(lw + j * 4 + 4);
            const int sa = ls[j], sb = ls[j + 1];
            const uint2 ha = *(const uint2*)((const char*)Xb + (((unsigned)sa) << 8) + myoff);
            const uint2 hb = *(const uint2*)((const char*)Xb + (((unsigned)sb) << 8) + myoff);
            F3_FMA(wa, ha)
            F3_FMA(wb, hb)
        }
        if (j < jn) {
            const float4 wa = *(const float4*)(lw + j * 4);
            const int sa = ls[j];
            const uint2 ha = *(const uint2*)((const char*)Xb + (((unsigned)sa) << 8) + myoff);
            F3_FMA(wa, ha)
        }
    }
    #undef F3_FMA

    // each half-wave covers all 128 feats of its node: no cross-group acc reduce needed
    #pragma unroll
    for (int m = 16; m; m >>= 1) {
        sv.x += __shfl_xor(sv.x, m); sv.y += __shfl_xor(sv.y, m);
        sv.z += __shfl_xor(sv.z, m); sv.w += __shfl_xor(sv.w, m);
    }
    float4 rs;
    rs.x = 1.f / (sv.x + 1e-16f); rs.y = 1.f / (sv.y + 1e-16f);
    rs.z = 1.f / (sv.z + 1e-16f); rs.w = 1.f / (sv.w + 1e-16f);
    if (l32 == 0) *(float4*)(dpk + (size_t)node * 8 + 4) = rs;

    unsigned short* gr = gout + (size_t)node * 512 + 4 * l32;
    uint2 p0, p1, p2, p3;
    p0.x = pk2(acc2[0][0].x * rs.x, acc2[0][0].y * rs.x);
    p0.y = pk2(acc2[0][1].x * rs.x, acc2[0][1].y * rs.x);
    p1.x = pk2(acc2[1][0].x * rs.y, acc2[1][0].y * rs.y);
    p1.y = pk2(acc2[1][1].x * rs.y, acc2[1][1].y * rs.y);
    p2.x = pk2(acc2[2][0].x * rs.z, acc2[2][0].y * rs.z);
    p2.y = pk2(acc2[2][1].x * rs.z, acc2[2][1].y * rs.z);
    p3.x = pk2(acc2[3][0].x * rs.w, acc2[3][0].y * rs.w);
    p3.y = pk2(acc2[3][1].x * rs.w, acc2[3][1].y * rs.w);
    *(uint2*)(gr)       = p0;
    *(uint2*)(gr + 128) = p1;
    *(uint2*)(gr + 256) = p2;
    *(uint2*)(gr + 384) = p3;
}

// ---------------- per-layer alpha output, edge order (L2-resident gathers) ----------------
__global__ __launch_bounds__(256) void alpha_l_k(
    const int2* __restrict__ edges, const float* __restrict__ as_,
    const float* __restrict__ dpk, float* __restrict__ al)
{
    const int e = blockIdx.x * 256 + threadIdx.x;   // E exact
    const int2 v = edges[e];
    const float4 as4 = *(const float4*)(as_ + (size_t)v.x * 4);
    const float4 ad4 = *(const float4*)(dpk + (size_t)v.y * 8);
    const float4 r   = *(const float4*)(dpk + (size_t)v.y * 8 + 4);
    const float4 w = edge_w(as4, ad4);
    float4 a; a.x = w.x * r.x; a.y = w.y * r.y; a.z = w.z * r.z; a.w = w.w * r.w;
    *(float4*)(al + (size_t)e * 4) = a;
}

// ---------------- layer-3 projection: out = 0.25 * g[N,512] @ Wstack + b3 (MFMA) ----------------
__global__ __launch_bounds__(256) void proj3_k(
    const unsigned short* __restrict__ Gb, const unsigned short* __restrict__ Wt3,
    const float* __restrict__ b3, float* __restrict__ out)
{
    const int tile = blockIdx.x * 4 + (threadIdx.x >> 6);
    if (tile >= 3125) return;
    const int l = threadIdx.x & 63;
    const int lr = l & 15, lq = l >> 4;
    const int m0 = tile * 16;
    f32x4 acc[4];
    #pragma unroll
    for (int nt = 0; nt < 4; nt++) { acc[nt][0]=0.f; acc[nt][1]=0.f; acc[nt][2]=0.f; acc[nt][3]=0.f; }
    #pragma unroll
    for (int kb = 0; kb < 16; kb++) {               // K=512
        const int h = kb >> 2;
        const int kk = (kb & 3) * 32 + lq * 8;      // k within [0,128)
        const bf16x8 a = *(const bf16x8*)(Gb + (size_t)(m0 + lr) * 512 + kb * 32 + lq * 8);
        #pragma unroll
        for (int nt = 0; nt < 4; nt++) {
            const int c = nt * 16 + lr;
            const bf16x8 b = *(const bf16x8*)(Wt3 + (size_t)(h * 64 + c) * 128 + kk);
            acc[nt] = __builtin_amdgcn_mfma_f32_16x16x32_bf16(a, b, acc[nt], 0, 0, 0);
        }
    }
    #pragma unroll
    for (int nt = 0; nt < 4; nt++)
        #pragma unroll
        for (int r = 0; r < 4; r++) {
            const int col = nt * 16 + lr;
            out[(size_t)(m0 + lq * 4 + r) * 64 + col] = 0.25f * acc[nt][r] + b3[col];
        }
}

extern "C" void kernel_launch(void* const* d_in, const int* in_sizes, int n_in,
                              void* d_out, int out_size, void* d_ws, size_t ws_size,
                              hipStream_t stream)
{
    char* ws = (char*)d_ws;
    unsigned short* g_bf    = (unsigned short*)(ws);              // [N,512] bf16 (51.2 MB), layer 3 only
    int2*           bedges  = (int2*)(ws);                        // ALIAS of g_bf: bucket-sorted edges (12.8 MB), CSR build only
    int*            csrc    = (int*)(ws + 51200000);              // [E] src in CSR order (6.4 MB)
    unsigned short* x_bf    = (unsigned short*)(ws + 57600000);   // [N,128] bf16
    unsigned short* xcur_bf = (unsigned short*)(ws + 70400000);   // [N,128] bf16
    unsigned short* skip_bf = (unsigned short*)(ws + 83200000);   // [N,128] bf16
    unsigned short* Hbuf    = (unsigned short*)(ws + 96000000);   // [N,128] bf16
    int2*  edges  = (int2*)(ws + 108800000);                      // [E] (12.8 MB)
    float* as1b   = (float*)(ws + 121600000);                     // 3 x [N,4] + 3 x [N,8] f32
    float* as2b   = as1b + 200000;
    float* as3b   = as1b + 400000;
    float* dpk1   = as1b + 600000;                                // [N,8]: ad(4), rs(4)
    float* dpk2   = as1b + 1000000;
    float* dpk3   = as1b + 1400000;
    int*   roff   = (int*)(ws + 128800000);
    int*   deg    = (int*)(ws + 129000000);
    int*   bsum   = (int*)(ws + 129200000);
    int*   flags  = (int*)(ws + 129402048);
    unsigned short* Wt1 = (unsigned short*)(ws + 129500000);      // [128,128]
    unsigned short* Wts = Wt1 + 16384;
    unsigned short* Wt2 = Wts + 16384;
    unsigned short* Wt3 = Wt2 + 16384;                            // [256,128]
    float* smalls = (float*)(ws + 129700000);                     // 2432 f32
    float* vsrc   = (float*)(ws + 129720000);                     // [4,128]
    float* vdst   = (float*)(ws + 129730000);                     // [4,128]
    int*   cnt    = (int*)(ws + 130000000);                       // [NB*G1] = 613 KB
    int*   bsum2  = (int*)(ws + 130700000);                       // [B1]
    int*   bstart = (int*)(ws + 130710000);                       // [NB+1]

    float* as1c = smalls;          float* ad1c = smalls + 128;
    float* b1c  = smalls + 256;    float* l1wc = smalls + 384;
    float* l1bc = smalls + 512;    float* bskc = smalls + 640;
    float* as2c = smalls + 768;    float* ad2c = smalls + 896;
    float* b2c  = smalls + 1024;   float* l2wc = smalls + 1152;
    float* l2bc = smalls + 1280;   float* as3c = smalls + 1408;
    float* ad3c = smalls + 1664;   float* b3c  = smalls + 1920;

    float* out = (float*)d_out;
    float* al1 = out + (size_t)NN * 64;
    float* al2 = al1 + (size_t)EE * 4;
    float* al3 = al2 + (size_t)EE * 4;

    // ---------------- normalize + CSR build (deterministic 3-pass radix) ----------------
    detect_k<<<1, 256, 0, stream>>>(d_in[1], d_in[0], flags);
    hipMemsetAsync(deg, 0, NN * sizeof(int), stream);
    hist1_k<<<G1, 256, 0, stream>>>(d_in[1], flags, edges, cnt, deg);
    cvt_all_k<<<25330, 256, 0, stream>>>(
        d_in[0], d_in[2], d_in[8], d_in[10], d_in[16],
        d_in[3], d_in[4], d_in[5], d_in[6], d_in[7],
        d_in[9], d_in[11], d_in[12], d_in[13], d_in[14], d_in[15],
        d_in[17], d_in[18], d_in[19],
        x_bf, Wt1, Wts, Wt2, Wt3, smalls, flags);
    scanAg_k<<<B1, 256, 0, stream>>>(cnt, bsum2);
    scanBg_k<<<1, 256, 0, stream>>>(bsum2);
    scanCg_k<<<B1, 256, 0, stream>>>(cnt, bsum2, bstart);
    scatter_k<<<G1, 256, 0, stream>>>(edges, cnt, bedges);
    scanA_k<<<SCAN_B, 256, 0, stream>>>(deg, roff, bsum);
    scanB_k<<<1, 256, 0, stream>>>(bsum);
    scanC_k<<<SCAN_B, 256, 0, stream>>>(roff, bsum);
    place_k<<<NB, 256, 0, stream>>>(bedges, bstart, roff, csrc);
    prep_v_k<<<2, 256, 0, stream>>>(Wt3, as3c, ad3c, vsrc, vdst);

    // ---------------- layer 1 (matmul + fused dots1) ----------------
    mm12_k<<<782, 256, 0, stream>>>(x_bf, Wt1, Hbuf, skip_bf, as1c, ad1c, as1b, dpk1);
    fagg12_k<true, false><<<6250, 256, 0, stream>>>(roff, deg, csrc, as1b, dpk1, Hbuf,
                                                    b1c, l1wc, l1bc, skip_bf, bskc, xcur_bf,
                                                    nullptr, nullptr, nullptr, nullptr);

    // ---------------- layer 2 (matmul + fused dots2; fagg fuses dots3) ----------------
    mfma_mm_k<128, true><<<782, 256, 0, stream>>>(xcur_bf, Wt2, Hbuf, as2c, ad2c, as2b, dpk2);
    fagg12_k<false, true><<<6250, 256, 0, stream>>>(roff, deg, csrc, as2b, dpk2, Hbuf,
                                                    b2c, l2wc, l2bc, nullptr, nullptr, xcur_bf,
                                                    vsrc, vdst, as3b, dpk3);

    // ---------------- layer 3 ----------------
    fagg3_k<<<6250, 256, 0, stream>>>(roff, deg, csrc, as3b, dpk3, xcur_bf, g_bf);
    proj3_k<<<782, 256, 0, stream>>>(g_bf, Wt3, b3c, out);

    // ---------------- alpha outputs, one kernel per layer (small L2-resident tables) ----------------
    alpha_l_k<<<6250, 256, 0, stream>>>(edges, as1b, dpk1, al1);
    alpha_l_k<<<6250, 256, 0, stream>>>(edges, as2b, dpk2, al2);
    alpha_l_k<<<6250, 256, 0, stream>>>(edges, as3b, dpk3, al3);
}

// Round 11
// 566.897 us; speedup vs baseline: 1.0992x; 1.0992x over previous
//
#include <hip/hip_runtime.h>

#define NN 50000
#define EE 1600000
#define SCAN_B 196   // ceil(NN/256)
#define NB 196       // buckets = dst >> 8
#define CHUNK 2048   // edges per wg in radix passes
#define G1 782       // ceil(EE/CHUNK)
#define L1 (NB * G1) // count-matrix length = 153272
#define B1 599       // ceil(L1/256)

typedef __attribute__((ext_vector_type(8))) short bf16x8;
typedef __attribute__((ext_vector_type(4))) float f32x4;
typedef __attribute__((ext_vector_type(2))) float f32x2;

#if __has_builtin(__builtin_elementwise_fma)
#define PKFMA(a, b, c) __builtin_elementwise_fma((a), (b), (c))
#else
#define PKFMA(a, b, c) ((a) * (b) + (c))
#endif

__device__ __forceinline__ float bfu(unsigned short u) { return __uint_as_float((unsigned)u << 16); }
__device__ __forceinline__ float bflo(unsigned u) { return __uint_as_float(u << 16); }
__device__ __forceinline__ float bfhi(unsigned u) { return __uint_as_float(u & 0xffff0000u); }
__device__ __forceinline__ f32x2 bfpk(unsigned u) {
    f32x2 r; r.x = bflo(u); r.y = bfhi(u); return r;
}
__device__ __forceinline__ unsigned short f2bf(float f) {   // RNE f32->bf16
    unsigned u = __float_as_uint(f);
    u += 0x7fff + ((u >> 16) & 1);
    return (unsigned short)(u >> 16);
}
__device__ __forceinline__ unsigned pk2(float a, float b) {
    return (unsigned)f2bf(a) | ((unsigned)f2bf(b) << 16);
}
__device__ __forceinline__ float cvt_load(const void* p, int i, bool f32) {
    if (f32) return ((const float*)p)[i];
    return bfu(((const unsigned short*)p)[i]);
}

// ---------------- dtype detection ----------------
__global__ void detect_k(const void* ei_raw, const void* x_raw, int* flags) {
    __shared__ int s_i64, s_f32;
    const int t = threadIdx.x;
    if (t == 0) { s_i64 = 1; s_f32 = 0; }
    __syncthreads();
    const int* ei32 = (const int*)ei_raw;
    if (ei32[2 * t + 1] != 0) atomicAnd(&s_i64, 0);
    const unsigned short* xu = (const unsigned short*)x_raw;
    int found = 0;
    for (int j = 0; j < 32; j++) {
        unsigned short u = xu[t * 32 + j];
        if ((u & 0x7F80) == 0x7F80) found = 1;
    }
    if (found) atomicOr(&s_f32, 1);
    __syncthreads();
    if (t == 0) { flags[0] = s_i64; flags[1] = s_f32; }
}

// ---------------- radix pass 1: normalize + per-(bucket,wg) histogram ----------------
__global__ __launch_bounds__(256) void hist1_k(const void* ei_raw, const int* flags,
                                               int2* __restrict__ edges, int* __restrict__ cnt)
{
    __shared__ int h[NB];
    const int t = threadIdx.x;
    const int i64 = __builtin_amdgcn_readfirstlane(flags[0]);
    if (t < NB) h[t] = 0;
    __syncthreads();
    const int beg = blockIdx.x * CHUNK;
    const int end = min(beg + CHUNK, EE);
    for (int e = beg + t; e < end; e += 256) {
        int2 v;
        if (i64) { const long long* p = (const long long*)ei_raw; v.x = (int)p[e]; v.y = (int)p[EE + e]; }
        else     { const int* p = (const int*)ei_raw;             v.x = p[e];      v.y = p[EE + e];      }
        edges[e] = v;
        atomicAdd(&h[v.y >> 8], 1);
    }
    __syncthreads();
    if (t < NB) cnt[(size_t)t * G1 + blockIdx.x] = h[t];
}

// ---------------- generic scan over cnt[L1] (3-phase) ----------------
__global__ __launch_bounds__(256) void scanAg_k(int* __restrict__ cnt, int* __restrict__ bsum2) {
    __shared__ int ps[256];
    const int b = blockIdx.x, t = threadIdx.x;
    const int i = b * 256 + t;
    const int v = (i < L1) ? cnt[i] : 0;
    ps[t] = v;
    __syncthreads();
    for (int off = 1; off < 256; off <<= 1) {
        const int u = (t >= off) ? ps[t - off] : 0;
        __syncthreads();
        ps[t] += u;
        __syncthreads();
    }
    if (i < L1) cnt[i] = ps[t] - v;            // local exclusive
    if (t == 255) bsum2[b] = ps[255];
}
__global__ void scanBg_k(int* bsum2) {
    __shared__ int ps[256];
    const int t = threadIdx.x;
    int vals[3];
    int s = 0;
    #pragma unroll
    for (int i = 0; i < 3; i++) {
        const int idx = t * 3 + i;
        vals[i] = (idx < B1) ? bsum2[idx] : 0;
        s += vals[i];
    }
    ps[t] = s;
    __syncthreads();
    for (int off = 1; off < 256; off <<= 1) {
        const int u = (t >= off) ? ps[t - off] : 0;
        __syncthreads();
        ps[t] += u;
        __syncthreads();
    }
    int run = t ? ps[t - 1] : 0;
    #pragma unroll
    for (int i = 0; i < 3; i++) {
        const int idx = t * 3 + i;
        if (idx < B1) bsum2[idx] = run;
        run += vals[i];
    }
}
__global__ __launch_bounds__(256) void scanCg_k(int* __restrict__ cnt, const int* __restrict__ bsum2,
                                                int* __restrict__ bstart) {
    const int i = blockIdx.x * 256 + threadIdx.x;
    if (i < L1) {
        const int r = cnt[i] + bsum2[blockIdx.x];
        cnt[i] = r;
        if (i % G1 == 0) bstart[i / G1] = r;
    }
    if (i == 0) bstart[NB] = EE;
}

// ---------------- radix pass 2: deterministic scatter into bucket-contiguous bedges ----------------
__global__ __launch_bounds__(256) void scatter_k(const int2* __restrict__ edges,
                                                 const int* __restrict__ cnt,
                                                 int2* __restrict__ bedges)
{
    __shared__ int ofs[NB];
    const int t = threadIdx.x;
    if (t < NB) ofs[t] = cnt[(size_t)t * G1 + blockIdx.x];
    __syncthreads();
    const int beg = blockIdx.x * CHUNK;
    const int end = min(beg + CHUNK, EE);
    for (int e = beg + t; e < end; e += 256) {
        const int2 v = edges[e];
        const int p = atomicAdd(&ofs[v.y >> 8], 1);        // LDS atomic
        bedges[p] = v;
    }
}

// ---------------- per-bucket histogram -> deg ----------------
__global__ __launch_bounds__(256) void hist_k(const int2* __restrict__ bedges,
                                              const int* __restrict__ bstart, int* __restrict__ deg)
{
    __shared__ int h[256];
    const int b = blockIdx.x, t = threadIdx.x;
    h[t] = 0;
    __syncthreads();
    const int lo = bstart[b], hi = bstart[b + 1];
    for (int i = lo + t; i < hi; i += 256)
        atomicAdd(&h[bedges[i].y & 255], 1);
    __syncthreads();
    const int d = b * 256 + t;
    if (d < NN) deg[d] = h[t];
}

// ---------------- node-level 3-phase scan ----------------
__global__ __launch_bounds__(256) void scanA_k(const int* __restrict__ deg,
                                               int* __restrict__ roff, int* __restrict__ bsum) {
    __shared__ int ps[256];
    const int b = blockIdx.x, t = threadIdx.x;
    const int i = b * 256 + t;
    const int v = (i < NN) ? deg[i] : 0;
    ps[t] = v;
    __syncthreads();
    for (int off = 1; off < 256; off <<= 1) {
        const int u = (t >= off) ? ps[t - off] : 0;
        __syncthreads();
        ps[t] += u;
        __syncthreads();
    }
    if (i < NN) roff[i] = ps[t] - v;           // local exclusive
    if (t == 255) bsum[b] = ps[255];
}
__global__ void scanB_k(int* bsum) {
    __shared__ int ps[256];
    const int t = threadIdx.x;
    const int v = (t < SCAN_B) ? bsum[t] : 0;
    ps[t] = v;
    __syncthreads();
    for (int off = 1; off < 256; off <<= 1) {
        const int u = (t >= off) ? ps[t - off] : 0;
        __syncthreads();
        ps[t] += u;
        __syncthreads();
    }
    if (t < SCAN_B) bsum[t] = ps[t] - v;       // exclusive block base
}
__global__ __launch_bounds__(256) void scanC_k(int* __restrict__ roff, const int* __restrict__ bsum) {
    const int b = blockIdx.x, t = threadIdx.x;
    const int i = b * 256 + t;
    if (i < NN) roff[i] += bsum[b];
}

// ---------------- per-bucket CSR placement (LDS cursors; writes confined to one wg) ----------------
__global__ __launch_bounds__(256) void place_k(const int2* __restrict__ bedges,
                                               const int* __restrict__ bstart, const int* __restrict__ roff,
                                               int* __restrict__ csrc)
{
    __shared__ int cur[256];
    const int b = blockIdx.x, t = threadIdx.x;
    const int d = b * 256 + t;
    cur[t] = (d < NN) ? roff[d] : 0;
    __syncthreads();
    const int lo = bstart[b], hi = bstart[b + 1];
    for (int i = lo + t; i < hi; i += 256) {
        const int2 v = bedges[i];
        const int p = atomicAdd(&cur[v.y & 255], 1);       // LDS atomic
        csrc[p] = v.x;
    }
}

// ---------------- normalize: x->bf16, W->transposed bf16, smalls->f32 ----------------
__global__ __launch_bounds__(256) void cvt_all_k(
    const void* x, const void* W1, const void* Wskip, const void* W2, const void* W3,
    const void* as1, const void* ad1, const void* b1, const void* l1w, const void* l1b,
    const void* bsk, const void* as2, const void* ad2, const void* b2, const void* l2w,
    const void* l2b, const void* as3, const void* ad3, const void* b3,
    unsigned short* xb, unsigned short* Wt1, unsigned short* Wts, unsigned short* Wt2,
    unsigned short* Wt3, float* smalls, const int* flags)
{
    const bool f32 = __builtin_amdgcn_readfirstlane(flags[1]) != 0;
    const int gid = blockIdx.x * 256 + threadIdx.x;
    if (gid < NN * 128) { xb[gid] = f2bf(cvt_load(x, gid, f32)); return; }
    int g = gid - NN * 128;
    if (g < 16384) { Wt1[g] = f2bf(cvt_load(W1,    (g & 127) * 128 + (g >> 7), f32)); return; }
    g -= 16384;
    if (g < 16384) { Wts[g] = f2bf(cvt_load(Wskip, (g & 127) * 128 + (g >> 7), f32)); return; }
    g -= 16384;
    if (g < 16384) { Wt2[g] = f2bf(cvt_load(W2,    (g & 127) * 128 + (g >> 7), f32)); return; }
    g -= 16384;
    if (g < 32768) { Wt3[g] = f2bf(cvt_load(W3,    (g & 127) * 256 + (g >> 7), f32)); return; }
    g -= 32768;
    if (g >= 2432) return;
    const void* src; int off;
    if      (g < 128)  { src = as1; off = g;        }
    else if (g < 256)  { src = ad1; off = g - 128;  }
    else if (g < 384)  { src = b1;  off = g - 256;  }
    else if (g < 512)  { src = l1w; off = g - 384;  }
    else if (g < 640)  { src = l1b; off = g - 512;  }
    else if (g < 768)  { src = bsk; off = g - 640;  }
    else if (g < 896)  { src = as2; off = g - 768;  }
    else if (g < 1024) { src = ad2; off = g - 896;  }
    else if (g < 1152) { src = b2;  off = g - 1024; }
    else if (g < 1280) { src = l2w; off = g - 1152; }
    else if (g < 1408) { src = l2b; off = g - 1280; }
    else if (g < 1664) { src = as3; off = g - 1408; }
    else if (g < 1920) { src = ad3; off = g - 1664; }
    else               { src = b3;  off = g - 1920; }
    smalls[g] = cvt_load(src, off, f32);
}

// ---------------- v_h = W3_h @ a3_h composites (for layer-3 logits) ----------------
__global__ void prep_v_k(const unsigned short* __restrict__ Wt3, const float* __restrict__ as3,
                         const float* __restrict__ ad3, float* __restrict__ vsrc, float* __restrict__ vdst)
{
    const int t = blockIdx.x * 256 + threadIdx.x;   // 512 total
    if (t >= 512) return;
    const int h = t >> 7, k = t & 127;
    float ss = 0.f, dd = 0.f;
    for (int c = 0; c < 64; c++) {
        const float w = bfu(Wt3[(size_t)(h * 64 + c) * 128 + k]);
        ss = fmaf(w, as3[h * 64 + c], ss);
        dd = fmaf(w, ad3[h * 64 + c], dd);
    }
    vsrc[t] = ss; vdst[t] = dd;
}

// ---------------- MFMA matmul + optional fused attention dots ----------------
template<int FOUT, bool DOTS>
__global__ __launch_bounds__(256) void mfma_mm_k(
    const unsigned short* __restrict__ Xb, const unsigned short* __restrict__ Wt,
    unsigned short* __restrict__ Hb,
    const float* __restrict__ asrc, const float* __restrict__ adst,
    float* __restrict__ as_, float* __restrict__ dpk)
{
    constexpr int NT = FOUT / 16;
    const int tile = blockIdx.x * 4 + (threadIdx.x >> 6);
    if (tile >= 3125) return;                       // 50000 = 3125*16
    const int l = threadIdx.x & 63;
    const int lr = l & 15, lq = l >> 4;
    const int m0 = tile * 16;
    f32x4 acc[NT];
    #pragma unroll
    for (int nt = 0; nt < NT; nt++) { acc[nt][0]=0.f; acc[nt][1]=0.f; acc[nt][2]=0.f; acc[nt][3]=0.f; }
    #pragma unroll
    for (int kb = 0; kb < 4; kb++) {                // K=128 = 4*32
        const bf16x8 a = *(const bf16x8*)(Xb + (size_t)(m0 + lr) * 128 + kb * 32 + lq * 8);
        #pragma unroll
        for (int nt = 0; nt < NT; nt++) {
            const bf16x8 b = *(const bf16x8*)(Wt + (size_t)(nt * 16 + lr) * 128 + kb * 32 + lq * 8);
            acc[nt] = __builtin_amdgcn_mfma_f32_16x16x32_bf16(a, b, acc[nt], 0, 0, 0);
        }
    }
    #pragma unroll
    for (int nt = 0; nt < NT; nt++)
        #pragma unroll
        for (int r = 0; r < 4; r++)
            Hb[(size_t)(m0 + lq * 4 + r) * FOUT + nt * 16 + lr] = f2bf(acc[nt][r]);
    if (DOTS) {
        #pragma unroll
        for (int hd = 0; hd < 4; hd++) {
            const float a0 = asrc[hd * 32 + lr], a1 = asrc[hd * 32 + 16 + lr];
            const float d0 = adst[hd * 32 + lr], d1 = adst[hd * 32 + 16 + lr];
            #pragma unroll
            for (int r = 0; r < 4; r++) {
                float ps = acc[2 * hd][r] * a0 + acc[2 * hd + 1][r] * a1;
                float pd = acc[2 * hd][r] * d0 + acc[2 * hd + 1][r] * d1;
                #pragma unroll
                for (int m = 8; m; m >>= 1) { ps += __shfl_xor(ps, m); pd += __shfl_xor(pd, m); }
                if (lr == 0) {
                    const int node = m0 + lq * 4 + r;
                    as_[(size_t)node * 4 + hd] = ps;
                    dpk[(size_t)node * 8 + hd] = pd;
                }
            }
        }
    }
}

// ---------------- fused layer-1 matmul: H = X@W1t^T, S = X@Wst^T, + dots1 ----------------
__global__ __launch_bounds__(256) void mm12_k(
    const unsigned short* __restrict__ Xb, const unsigned short* __restrict__ Wt1,
    unsigned short* __restrict__ Hb, unsigned short* __restrict__ Sb,
    const float* __restrict__ asrc, const float* __restrict__ adst,
    float* __restrict__ as_, float* __restrict__ dpk)
{
    const int tile = blockIdx.x * 4 + (threadIdx.x >> 6);
    if (tile >= 3125) return;
    const int l = threadIdx.x & 63;
    const int lr = l & 15, lq = l >> 4;
    const int m0 = tile * 16;
    f32x4 acc[16];
    #pragma unroll
    for (int nt = 0; nt < 16; nt++) { acc[nt][0]=0.f; acc[nt][1]=0.f; acc[nt][2]=0.f; acc[nt][3]=0.f; }
    #pragma unroll
    for (int kb = 0; kb < 4; kb++) {
        const bf16x8 a = *(const bf16x8*)(Xb + (size_t)(m0 + lr) * 128 + kb * 32 + lq * 8);
        #pragma unroll
        for (int nt = 0; nt < 16; nt++) {
            const bf16x8 b = *(const bf16x8*)(Wt1 + (size_t)(nt * 16 + lr) * 128 + kb * 32 + lq * 8);
            acc[nt] = __builtin_amdgcn_mfma_f32_16x16x32_bf16(a, b, acc[nt], 0, 0, 0);
        }
    }
    #pragma unroll
    for (int nt = 0; nt < 8; nt++)
        #pragma unroll
        for (int r = 0; r < 4; r++)
            Hb[(size_t)(m0 + lq * 4 + r) * 128 + nt * 16 + lr] = f2bf(acc[nt][r]);
    #pragma unroll
    for (int nt = 8; nt < 16; nt++)
        #pragma unroll
        for (int r = 0; r < 4; r++)
            Sb[(size_t)(m0 + lq * 4 + r) * 128 + (nt - 8) * 16 + lr] = f2bf(acc[nt][r]);
    #pragma unroll
    for (int hd = 0; hd < 4; hd++) {
        const float a0 = asrc[hd * 32 + lr], a1 = asrc[hd * 32 + 16 + lr];
        const float d0 = adst[hd * 32 + lr], d1 = adst[hd * 32 + 16 + lr];
        #pragma unroll
        for (int r = 0; r < 4; r++) {
            float ps = acc[2 * hd][r] * a0 + acc[2 * hd + 1][r] * a1;
            float pd = acc[2 * hd][r] * d0 + acc[2 * hd + 1][r] * d1;
            #pragma unroll
            for (int m = 8; m; m >>= 1) { ps += __shfl_xor(ps, m); pd += __shfl_xor(pd, m); }
            if (lr == 0) {
                const int node = m0 + lq * 4 + r;
                as_[(size_t)node * 4 + hd] = ps;
                dpk[(size_t)node * 8 + hd] = pd;
            }
        }
    }
}

__device__ __forceinline__ float4 edge_w(float4 as4, float4 ad4) {
    float4 e4;
    e4.x = as4.x + ad4.x; e4.y = as4.y + ad4.y; e4.z = as4.z + ad4.z; e4.w = as4.w + ad4.w;
    e4.x = e4.x >= 0.f ? e4.x : 0.2f * e4.x;
    e4.y = e4.y >= 0.f ? e4.y : 0.2f * e4.y;
    e4.z = e4.z >= 0.f ? e4.z : 0.2f * e4.z;
    e4.w = e4.w >= 0.f ? e4.w : 0.2f * e4.w;
    float4 w4;
    w4.x = __expf(e4.x); w4.y = __expf(e4.y); w4.z = __expf(e4.z); w4.w = __expf(e4.w);
    return w4;
}

// ---------------- fused edge phase, layers 1/2: 2 nodes per wave (half-wave each) ----------------
template<bool HAS_SKIP, bool DOTS3>
__global__ __launch_bounds__(256) void fagg12_k(
    const int* __restrict__ roff, const int* __restrict__ deg,
    const int* __restrict__ csrc, const float* __restrict__ as_, float* __restrict__ dpk,
    const unsigned short* __restrict__ Hb,
    const float* __restrict__ b, const float* __restrict__ lnw, const float* __restrict__ lnb,
    const unsigned short* __restrict__ skipb, const float* __restrict__ bskip,
    unsigned short* __restrict__ xoutb,
    const float* __restrict__ vsrc, const float* __restrict__ vdst,
    float* __restrict__ as3o, float* __restrict__ dpk3o)
{
    __shared__ float lws[4][512];                   // per wave: 2 halves x 32 edges x [w0,s,w1,s,w2,s,w3,s]
    const int warp = threadIdx.x >> 6;
    const int lane = threadIdx.x & 63;
    const int half = lane >> 5;                     // node selector within wave
    const int l32  = lane & 31;
    const int node = blockIdx.x * 8 + warp * 2 + half;
    const int q = l32 & 15, g = l32 >> 4;           // features 8q..8q+7 ; edge group g (0/1)
    const int h = q >> 2;                           // head of this lane's features
    float* lw = lws[warp] + half * 256;
    const int ro = roff[node], dg = deg[node];
    const float4 ad4 = *(const float4*)(dpk + (size_t)node * 8);

    float4 sv = make_float4(0.f, 0.f, 0.f, 0.f);
    f32x2 acc2[4];
    #pragma unroll
    for (int i = 0; i < 4; i++) { acc2[i].x = 0.f; acc2[i].y = 0.f; }

    for (int j0 = 0; j0 < dg; j0 += 32) {
        const int jn = min(32, dg - j0);
        int src = 0;
        float4 w4 = make_float4(0.f, 0.f, 0.f, 0.f);
        if (l32 < jn) {
            src = csrc[ro + j0 + l32];
            const float4 as4 = *(const float4*)(as_ + (size_t)src * 4);
            w4 = edge_w(as4, ad4);
            sv.x += w4.x; sv.y += w4.y; sv.z += w4.z; sv.w += w4.w;
        }
        const float sf = __int_as_float(src);
        *(float4*)(lw + l32 * 8)     = make_float4(w4.x, sf, w4.y, sf);
        *(float4*)(lw + l32 * 8 + 4) = make_float4(w4.z, sf, w4.w, sf);
        const int jq = (jn + 1) >> 1;
        #pragma unroll 4
        for (int j = 0; j < jq; j++) {
            const int e = 2 * j + g;                // e==jn (odd tail) reads w=0 entry: harmless
            const float2 rd = *(const float2*)(lw + e * 8 + h * 2);  // (w_h, src bits) broadcast
            f32x2 ww; ww.x = rd.x; ww.y = rd.x;
            const unsigned soff = (__float_as_uint(rd.y) << 8) + (unsigned)(q << 4);
            const uint4 hv = *(const uint4*)((const char*)Hb + soff); // 16B of row
            acc2[0] = PKFMA(ww, bfpk(hv.x), acc2[0]);
            acc2[1] = PKFMA(ww, bfpk(hv.y), acc2[1]);
            acc2[2] = PKFMA(ww, bfpk(hv.z), acc2[2]);
            acc2[3] = PKFMA(ww, bfpk(hv.w), acc2[3]);
        }
    }

    // combine the 2 edge-groups' partial sums (stay within the 32-lane half)
    #pragma unroll
    for (int i = 0; i < 4; i++) {
        acc2[i].x += __shfl_xor(acc2[i].x, 16);
        acc2[i].y += __shfl_xor(acc2[i].y, 16);
    }
    #pragma unroll
    for (int m = 16; m; m >>= 1) {
        sv.x += __shfl_xor(sv.x, m); sv.y += __shfl_xor(sv.y, m);
        sv.z += __shfl_xor(sv.z, m); sv.w += __shfl_xor(sv.w, m);
    }
    float4 rs;
    rs.x = 1.f / (sv.x + 1e-16f); rs.y = 1.f / (sv.y + 1e-16f);
    rs.z = 1.f / (sv.z + 1e-16f); rs.w = 1.f / (sv.w + 1e-16f);
    if (l32 == 0) *(float4*)(dpk + (size_t)node * 8 + 4) = rs;
    const float rsh = (h == 0) ? rs.x : (h == 1) ? rs.y : (h == 2) ? rs.z : rs.w;

    // epilogue: bias -> elu -> LN (+skip) -> bf16 pack (both groups replicated; g==0 stores)
    const float4 b0 = *(const float4*)(b + q * 8);
    const float4 b1 = *(const float4*)(b + q * 8 + 4);
    float v[8];
    v[0] = acc2[0].x * rsh + b0.x; v[1] = acc2[0].y * rsh + b0.y;
    v[2] = acc2[1].x * rsh + b0.z; v[3] = acc2[1].y * rsh + b0.w;
    v[4] = acc2[2].x * rsh + b1.x; v[5] = acc2[2].y * rsh + b1.y;
    v[6] = acc2[3].x * rsh + b1.z; v[7] = acc2[3].y * rsh + b1.w;
    float s1 = 0.f, s2 = 0.f;
    #pragma unroll
    for (int i = 0; i < 8; i++) {
        v[i] = v[i] > 0.f ? v[i] : (__expf(v[i]) - 1.f);
        s1 += v[i]; s2 += v[i] * v[i];
    }
    #pragma unroll
    for (int m = 8; m; m >>= 1) { s1 += __shfl_xor(s1, m); s2 += __shfl_xor(s2, m); }
    const float mu   = s1 * (1.f / 128.f);
    const float var  = s2 * (1.f / 128.f) - mu * mu;
    const float rstd = rsqrtf(var + 1e-5f);
    const float4 w0 = *(const float4*)(lnw + q * 8);
    const float4 w1 = *(const float4*)(lnw + q * 8 + 4);
    const float4 o0 = *(const float4*)(lnb + q * 8);
    const float4 o1 = *(const float4*)(lnb + q * 8 + 4);
    float y[8];
    y[0] = (v[0] - mu) * rstd * w0.x + o0.x; y[1] = (v[1] - mu) * rstd * w0.y + o0.y;
    y[2] = (v[2] - mu) * rstd * w0.z + o0.z; y[3] = (v[3] - mu) * rstd * w0.w + o0.w;
    y[4] = (v[4] - mu) * rstd * w1.x + o1.x; y[5] = (v[5] - mu) * rstd * w1.y + o1.y;
    y[6] = (v[6] - mu) * rstd * w1.z + o1.z; y[7] = (v[7] - mu) * rstd * w1.w + o1.w;
    if (HAS_SKIP) {
        const uint4 sk = *(const uint4*)(skipb + (size_t)node * 128 + q * 8);
        const float4 k0 = *(const float4*)(bskip + q * 8);
        const float4 k1 = *(const float4*)(bskip + q * 8 + 4);
        y[0] += bflo(sk.x) + k0.x; y[1] += bfhi(sk.x) + k0.y;
        y[2] += bflo(sk.y) + k0.z; y[3] += bfhi(sk.y) + k0.w;
        y[4] += bflo(sk.z) + k1.x; y[5] += bfhi(sk.z) + k1.y;
        y[6] += bflo(sk.w) + k1.z; y[7] += bfhi(sk.w) + k1.w;
    }
    if (g == 0) {
        uint4 pk;
        pk.x = pk2(y[0], y[1]); pk.y = pk2(y[2], y[3]);
        pk.z = pk2(y[4], y[5]); pk.w = pk2(y[6], y[7]);
        *(uint4*)(xoutb + (size_t)node * 128 + q * 8) = pk;
    }
    if (DOTS3) {
        // layer-3 logits from register-resident y (feats 8q..8q+7)
        #pragma unroll
        for (int hd = 0; hd < 4; hd++) {
            const float4 vs0 = *(const float4*)(vsrc + hd * 128 + q * 8);
            const float4 vs1 = *(const float4*)(vsrc + hd * 128 + q * 8 + 4);
            const float4 vd0 = *(const float4*)(vdst + hd * 128 + q * 8);
            const float4 vd1 = *(const float4*)(vdst + hd * 128 + q * 8 + 4);
            float ss = y[0] * vs0.x + y[1] * vs0.y + y[2] * vs0.z + y[3] * vs0.w
                     + y[4] * vs1.x + y[5] * vs1.y + y[6] * vs1.z + y[7] * vs1.w;
            float dd = y[0] * vd0.x + y[1] * vd0.y + y[2] * vd0.z + y[3] * vd0.w
                     + y[4] * vd1.x + y[5] * vd1.y + y[6] * vd1.z + y[7] * vd1.w;
            #pragma unroll
            for (int m = 8; m; m >>= 1) { ss += __shfl_xor(ss, m); dd += __shfl_xor(dd, m); }
            if (l32 == 0) {
                as3o[(size_t)node * 4 + hd] = ss;
                dpk3o[(size_t)node * 8 + hd] = dd;
            }
        }
    }
}

// ---------------- layer-3 edge phase: 2 nodes/wave, 32 lanes/edge, 4x unrolled gathers ----------------
__global__ __launch_bounds__(256) void fagg3_k(
    const int* __restrict__ roff, const int* __restrict__ deg,
    const int* __restrict__ csrc, const float* __restrict__ as_, float* __restrict__ dpk,
    const unsigned short* __restrict__ Xb,
    unsigned short* __restrict__ gout)
{
    __shared__ float lws[4][256];                   // 2 halves x 32 edges x w4
    __shared__ int lss[4][64];                      // 2 halves x 32 src
    const int warp = threadIdx.x >> 6;
    const int lane = threadIdx.x & 63;
    const int half = lane >> 5;
    const int l32  = lane & 31;
    const int node = blockIdx.x * 8 + warp * 2 + half;
    float* lw = lws[warp] + half * 128;
    int*   ls = lss[warp] + half * 32;
    const int ro = roff[node], dg = deg[node];
    const float4 ad4 = *(const float4*)(dpk + (size_t)node * 8);

    float4 sv = make_float4(0.f, 0.f, 0.f, 0.f);
    f32x2 acc2[4][2];
    #pragma unroll
    for (int hh = 0; hh < 4; hh++)
        #pragma unroll
        for (int i = 0; i < 2; i++) { acc2[hh][i].x = 0.f; acc2[hh][i].y = 0.f; }

    const unsigned myoff = (unsigned)(l32 << 3);    // 8B feature slice: feats 4*l32..4*l32+3

    #define F3_FMA(W4, HV)                                                              \
        {                                                                               \
            const f32x2 x01 = bfpk((HV).x), x23 = bfpk((HV).y);                         \
            f32x2 w0; w0.x = (W4).x; w0.y = (W4).x;                                     \
            f32x2 w1; w1.x = (W4).y; w1.y = (W4).y;                                     \
            f32x2 w2; w2.x = (W4).z; w2.y = (W4).z;                                     \
            f32x2 w3; w3.x = (W4).w; w3.y = (W4).w;                                     \
            acc2[0][0] = PKFMA(w0, x01, acc2[0][0]); acc2[0][1] = PKFMA(w0, x23, acc2[0][1]); \
            acc2[1][0] = PKFMA(w1, x01, acc2[1][0]); acc2[1][1] = PKFMA(w1, x23, acc2[1][1]); \
            acc2[2][0] = PKFMA(w2, x01, acc2[2][0]); acc2[2][1] = PKFMA(w2, x23, acc2[2][1]); \
            acc2[3][0] = PKFMA(w3, x01, acc2[3][0]); acc2[3][1] = PKFMA(w3, x23, acc2[3][1]); \
        }

    for (int j0 = 0; j0 < dg; j0 += 32) {
        const int jn = min(32, dg - j0);
        int src = 0;
        float4 w4 = make_float4(0.f, 0.f, 0.f, 0.f);
        if (l32 < jn) {
            src = csrc[ro + j0 + l32];
            const float4 as4 = *(const float4*)(as_ + (size_t)src * 4);
            w4 = edge_w(as4, ad4);
            sv.x += w4.x; sv.y += w4.y; sv.z += w4.z; sv.w += w4.w;
        }
        *(float4*)(lw + l32 * 4) = w4;
        ls[l32] = src;
        int j = 0;
        for (; j + 4 <= jn; j += 4) {               // 4 independent gather chains in flight
            const float4 wa = *(const float4*)(lw + j * 4);
            const float4 wb = *(const float4*)(lw + j * 4 + 4);
            const float4 wc = *(const float4*)(lw + j * 4 + 8);
            const float4 wd = *(const float4*)(lw + j * 4 + 12);
            const int sa = ls[j], sb = ls[j + 1], sc = ls[j + 2], sd = ls[j + 3];
            const uint2 ha = *(const uint2*)((const char*)Xb + (((unsigned)sa) << 8) + myoff);
            const uint2 hb = *(const uint2*)((const char*)Xb + (((unsigned)sb) << 8) + myoff);
            const uint2 hc = *(const uint2*)((const char*)Xb + (((unsigned)sc) << 8) + myoff);
            const uint2 hd = *(const uint2*)((const char*)Xb + (((unsigned)sd) << 8) + myoff);
            F3_FMA(wa, ha)
            F3_FMA(wb, hb)
            F3_FMA(wc, hc)
            F3_FMA(wd, hd)
        }
        for (; j + 2 <= jn; j += 2) {
            const float4 wa = *(const float4*)(lw + j * 4);
            const float4 wb = *(const float4*)(lw + j * 4 + 4);
            const int sa = ls[j], sb = ls[j + 1];
            const uint2 ha = *(const uint2*)((const char*)Xb + (((unsigned)sa) << 8) + myoff);
            const uint2 hb = *(const uint2*)((const char*)Xb + (((unsigned)sb) << 8) + myoff);
            F3_FMA(wa, ha)
            F3_FMA(wb, hb)
        }
        if (j < jn) {
            const float4 wa = *(const float4*)(lw + j * 4);
            const int sa = ls[j];
            const uint2 ha = *(const uint2*)((const char*)Xb + (((unsigned)sa) << 8) + myoff);
            F3_FMA(wa, ha)
        }
    }
    #undef F3_FMA

    // each half-wave covers all 128 feats of its node: no cross-group acc reduce needed
    #pragma unroll
    for (int m = 16; m; m >>= 1) {
        sv.x += __shfl_xor(sv.x, m); sv.y += __shfl_xor(sv.y, m);
        sv.z += __shfl_xor(sv.z, m); sv.w += __shfl_xor(sv.w, m);
    }
    float4 rs;
    rs.x = 1.f / (sv.x + 1e-16f); rs.y = 1.f / (sv.y + 1e-16f);
    rs.z = 1.f / (sv.z + 1e-16f); rs.w = 1.f / (sv.w + 1e-16f);
    if (l32 == 0) *(float4*)(dpk + (size_t)node * 8 + 4) = rs;

    unsigned short* gr = gout + (size_t)node * 512 + 4 * l32;
    uint2 p0, p1, p2, p3;
    p0.x = pk2(acc2[0][0].x * rs.x, acc2[0][0].y * rs.x);
    p0.y = pk2(acc2[0][1].x * rs.x, acc2[0][1].y * rs.x);
    p1.x = pk2(acc2[1][0].x * rs.y, acc2[1][0].y * rs.y);
    p1.y = pk2(acc2[1][1].x * rs.y, acc2[1][1].y * rs.y);
    p2.x = pk2(acc2[2][0].x * rs.z, acc2[2][0].y * rs.z);
    p2.y = pk2(acc2[2][1].x * rs.z, acc2[2][1].y * rs.z);
    p3.x = pk2(acc2[3][0].x * rs.w, acc2[3][0].y * rs.w);
    p3.y = pk2(acc2[3][1].x * rs.w, acc2[3][1].y * rs.w);
    *(uint2*)(gr)       = p0;
    *(uint2*)(gr + 128) = p1;
    *(uint2*)(gr + 256) = p2;
    *(uint2*)(gr + 384) = p3;
}

// ---------------- per-layer alpha output, edge order (L2-resident gathers) ----------------
__global__ __launch_bounds__(256) void alpha_l_k(
    const int2* __restrict__ edges, const float* __restrict__ as_,
    const float* __restrict__ dpk, float* __restrict__ al)
{
    const int e = blockIdx.x * 256 + threadIdx.x;   // E exact
    const int2 v = edges[e];
    const float4 as4 = *(const float4*)(as_ + (size_t)v.x * 4);
    const float4 ad4 = *(const float4*)(dpk + (size_t)v.y * 8);
    const float4 r   = *(const float4*)(dpk + (size_t)v.y * 8 + 4);
    const float4 w = edge_w(as4, ad4);
    float4 a; a.x = w.x * r.x; a.y = w.y * r.y; a.z = w.z * r.z; a.w = w.w * r.w;
    *(float4*)(al + (size_t)e * 4) = a;
}

// ---------------- layer-3 projection: out = 0.25 * g[N,512] @ Wstack + b3 (MFMA) ----------------
__global__ __launch_bounds__(256) void proj3_k(
    const unsigned short* __restrict__ Gb, const unsigned short* __restrict__ Wt3,
    const float* __restrict__ b3, float* __restrict__ out)
{
    const int tile = blockIdx.x * 4 + (threadIdx.x >> 6);
    if (tile >= 3125) return;
    const int l = threadIdx.x & 63;
    const int lr = l & 15, lq = l >> 4;
    const int m0 = tile * 16;
    f32x4 acc[4];
    #pragma unroll
    for (int nt = 0; nt < 4; nt++) { acc[nt][0]=0.f; acc[nt][1]=0.f; acc[nt][2]=0.f; acc[nt][3]=0.f; }
    #pragma unroll
    for (int kb = 0; kb < 16; kb++) {               // K=512
        const int h = kb >> 2;
        const int kk = (kb & 3) * 32 + lq * 8;      // k within [0,128)
        const bf16x8 a = *(const bf16x8*)(Gb + (size_t)(m0 + lr) * 512 + kb * 32 + lq * 8);
        #pragma unroll
        for (int nt = 0; nt < 4; nt++) {
            const int c = nt * 16 + lr;
            const bf16x8 b = *(const bf16x8*)(Wt3 + (size_t)(h * 64 + c) * 128 + kk);
            acc[nt] = __builtin_amdgcn_mfma_f32_16x16x32_bf16(a, b, acc[nt], 0, 0, 0);
        }
    }
    #pragma unroll
    for (int nt = 0; nt < 4; nt++)
        #pragma unroll
        for (int r = 0; r < 4; r++) {
            const int col = nt * 16 + lr;
            out[(size_t)(m0 + lq * 4 + r) * 64 + col] = 0.25f * acc[nt][r] + b3[col];
        }
}

extern "C" void kernel_launch(void* const* d_in, const int* in_sizes, int n_in,
                              void* d_out, int out_size, void* d_ws, size_t ws_size,
                              hipStream_t stream)
{
    char* ws = (char*)d_ws;
    unsigned short* g_bf    = (unsigned short*)(ws);              // [N,512] bf16 (51.2 MB), layer 3 only
    int2*           bedges  = (int2*)(ws);                        // ALIAS of g_bf: bucket-sorted edges (12.8 MB), CSR build only
    int*            csrc    = (int*)(ws + 51200000);              // [E] src in CSR order (6.4 MB)
    unsigned short* x_bf    = (unsigned short*)(ws + 57600000);   // [N,128] bf16
    unsigned short* xcur_bf = (unsigned short*)(ws + 70400000);   // [N,128] bf16
    unsigned short* skip_bf = (unsigned short*)(ws + 83200000);   // [N,128] bf16
    unsigned short* Hbuf    = (unsigned short*)(ws + 96000000);   // [N,128] bf16
    int2*  edges  = (int2*)(ws + 108800000);                      // [E] (12.8 MB)
    float* as1b   = (float*)(ws + 121600000);                     // 3 x [N,4] + 3 x [N,8] f32
    float* as2b   = as1b + 200000;
    float* as3b   = as1b + 400000;
    float* dpk1   = as1b + 600000;                                // [N,8]: ad(4), rs(4)
    float* dpk2   = as1b + 1000000;
    float* dpk3   = as1b + 1400000;
    int*   roff   = (int*)(ws + 128800000);
    int*   deg    = (int*)(ws + 129000000);
    int*   bsum   = (int*)(ws + 129200000);
    int*   flags  = (int*)(ws + 129402048);
    unsigned short* Wt1 = (unsigned short*)(ws + 129500000);      // [128,128]
    unsigned short* Wts = Wt1 + 16384;
    unsigned short* Wt2 = Wts + 16384;
    unsigned short* Wt3 = Wt2 + 16384;                            // [256,128]
    float* smalls = (float*)(ws + 129700000);                     // 2432 f32
    float* vsrc   = (float*)(ws + 129720000);                     // [4,128]
    float* vdst   = (float*)(ws + 129730000);                     // [4,128]
    int*   cnt    = (int*)(ws + 130000000);                       // [NB*G1] = 613 KB
    int*   bsum2  = (int*)(ws + 130700000);                       // [B1]
    int*   bstart = (int*)(ws + 130710000);                       // [NB+1]

    float* as1c = smalls;          float* ad1c = smalls + 128;
    float* b1c  = smalls + 256;    float* l1wc = smalls + 384;
    float* l1bc = smalls + 512;    float* bskc = smalls + 640;
    float* as2c = smalls + 768;    float* ad2c = smalls + 896;
    float* b2c  = smalls + 1024;   float* l2wc = smalls + 1152;
    float* l2bc = smalls + 1280;   float* as3c = smalls + 1408;
    float* ad3c = smalls + 1664;   float* b3c  = smalls + 1920;

    float* out = (float*)d_out;
    float* al1 = out + (size_t)NN * 64;
    float* al2 = al1 + (size_t)EE * 4;
    float* al3 = al2 + (size_t)EE * 4;

    // ---------------- normalize + CSR build (deterministic 3-pass radix) ----------------
    detect_k<<<1, 256, 0, stream>>>(d_in[1], d_in[0], flags);
    hist1_k<<<G1, 256, 0, stream>>>(d_in[1], flags, edges, cnt);
    cvt_all_k<<<25330, 256, 0, stream>>>(
        d_in[0], d_in[2], d_in[8], d_in[10], d_in[16],
        d_in[3], d_in[4], d_in[5], d_in[6], d_in[7],
        d_in[9], d_in[11], d_in[12], d_in[13], d_in[14], d_in[15],
        d_in[17], d_in[18], d_in[19],
        x_bf, Wt1, Wts, Wt2, Wt3, smalls, flags);
    scanAg_k<<<B1, 256, 0, stream>>>(cnt, bsum2);
    scanBg_k<<<1, 256, 0, stream>>>(bsum2);
    scanCg_k<<<B1, 256, 0, stream>>>(cnt, bsum2, bstart);
    scatter_k<<<G1, 256, 0, stream>>>(edges, cnt, bedges);
    hist_k<<<NB, 256, 0, stream>>>(bedges, bstart, deg);
    scanA_k<<<SCAN_B, 256, 0, stream>>>(deg, roff, bsum);
    scanB_k<<<1, 256, 0, stream>>>(bsum);
    scanC_k<<<SCAN_B, 256, 0, stream>>>(roff, bsum);
    place_k<<<NB, 256, 0, stream>>>(bedges, bstart, roff, csrc);
    prep_v_k<<<2, 256, 0, stream>>>(Wt3, as3c, ad3c, vsrc, vdst);

    // ---------------- layer 1 (matmul + fused dots1) ----------------
    mm12_k<<<782, 256, 0, stream>>>(x_bf, Wt1, Hbuf, skip_bf, as1c, ad1c, as1b, dpk1);
    fagg12_k<true, false><<<6250, 256, 0, stream>>>(roff, deg, csrc, as1b, dpk1, Hbuf,
                                                    b1c, l1wc, l1bc, skip_bf, bskc, xcur_bf,
                                                    nullptr, nullptr, nullptr, nullptr);

    // ---------------- layer 2 (matmul + fused dots2; fagg fuses dots3) ----------------
    mfma_mm_k<128, true><<<782, 256, 0, stream>>>(xcur_bf, Wt2, Hbuf, as2c, ad2c, as2b, dpk2);
    fagg12_k<false, true><<<6250, 256, 0, stream>>>(roff, deg, csrc, as2b, dpk2, Hbuf,
                                                    b2c, l2wc, l2bc, nullptr, nullptr, xcur_bf,
                                                    vsrc, vdst, as3b, dpk3);

    // ---------------- layer 3 ----------------
    fagg3_k<<<6250, 256, 0, stream>>>(roff, deg, csrc, as3b, dpk3, xcur_bf, g_bf);
    proj3_k<<<782, 256, 0, stream>>>(g_bf, Wt3, b3c, out);

    // ---------------- alpha outputs, one kernel per layer (small L2-resident tables) ----------------
    alpha_l_k<<<6250, 256, 0, stream>>>(edges, as1b, dpk1, al1);
    alpha_l_k<<<6250, 256, 0, stream>>>(edges, as2b, dpk2, al2);
    alpha_l_k<<<6250, 256, 0, stream>>>(edges, as3b, dpk3, al3);
}